// Round 17
// baseline (826.641 us; speedup 1.0000x reference)
//
#include <hip/hip_runtime.h>

// ---------------------------------------------------------------------------
// TTT layer forward: B=4, L=8192, D=1024, H=16, HD=64, C=64, NC=128
// Round 17: r15 overlap (bf16 y) + postnorm fused into out-GEMM A-staging.
// ---------------------------------------------------------------------------

typedef __attribute__((ext_vector_type(8))) short short8;
typedef __attribute__((ext_vector_type(4))) float f32x4;
typedef __attribute__((ext_vector_type(4))) unsigned short us4;

__device__ __forceinline__ float bf2f(unsigned short s) {
  union { unsigned int u; float f; } c;
  c.u = ((unsigned int)s) << 16;
  return c.f;
}
__device__ __forceinline__ unsigned short f2bf(float f) {
  union { float f; unsigned int u; } c;
  c.f = f;
  unsigned int u = c.u;
  return (unsigned short)((u + 0x7FFFu + ((u >> 16) & 1u)) >> 16);
}
__device__ __forceinline__ unsigned cvtpk(float lo, float hi) {
  unsigned r;
  asm("v_cvt_pk_bf16_f32 %0, %1, %2" : "=v"(r) : "v"(lo), "v"(hi));
  return r;
}

__device__ __forceinline__ void gload_lds16(const void* g, void* l) {
  __builtin_amdgcn_global_load_lds(
      (const __attribute__((address_space(1))) unsigned int*)g,
      (__attribute__((address_space(3))) unsigned int*)l, 16, 0, 0);
}

__device__ __forceinline__ float dpp16_sum(float x) {
  int v = __float_as_int(x);
  x += __int_as_float(__builtin_amdgcn_update_dpp(v, v, 0xB1, 0xF, 0xF, true));
  v = __float_as_int(x);
  x += __int_as_float(__builtin_amdgcn_update_dpp(v, v, 0x4E, 0xF, 0xF, true));
  v = __float_as_int(x);
  x += __int_as_float(__builtin_amdgcn_update_dpp(v, v, 0x141, 0xF, 0xF, true));
  v = __float_as_int(x);
  x += __int_as_float(__builtin_amdgcn_update_dpp(v, v, 0x140, 0xF, 0xF, true));
  return x;
}

__device__ __forceinline__ void barrier_fast() {
  __builtin_amdgcn_sched_barrier(0);
  asm volatile("s_waitcnt lgkmcnt(0)" ::: "memory");
  __builtin_amdgcn_s_barrier();
  asm volatile("" ::: "memory");
  __builtin_amdgcn_sched_barrier(0);
}
__device__ __forceinline__ void bar_nowait() {
  __builtin_amdgcn_sched_barrier(0);
  asm volatile("" ::: "memory");
  __builtin_amdgcn_s_barrier();
  asm volatile("" ::: "memory");
  __builtin_amdgcn_sched_barrier(0);
}

// ---------------- conversion kernels ----------------
__global__ __launch_bounds__(256) void cvt_f32_bf16(
    const float* __restrict__ in, unsigned short* __restrict__ out, long n) {
  long i = ((long)blockIdx.x * 256 + threadIdx.x) * 4;
  if (i + 3 < n) {
    float4 v = *(const float4*)&in[i];
    us4 o = { f2bf(v.x), f2bf(v.y), f2bf(v.z), f2bf(v.w) };
    *(us4*)&out[i] = o;
  }
}

// Wcat (4096 rows): head h owns rows [h*256, h*256+256):
//   +0..63 wq rows, +64..127 wk, +128..191 wv, +192 lr_w, +193..255 zero
__global__ __launch_bounds__(256) void build_wcat(
    const float* __restrict__ wq, const float* __restrict__ wk,
    const float* __restrict__ wv, const float* __restrict__ lrw,
    const float* __restrict__ wqb, const float* __restrict__ wkb,
    const float* __restrict__ wvb, const float* __restrict__ lrb,
    unsigned short* __restrict__ Wcat, float* __restrict__ biasc) {
  int i = blockIdx.x * 256 + threadIdx.x;  // 0 .. 4096*1024-1
  int row = i >> 10, col = i & 1023;
  int h = row >> 8, o = row & 255;
  float v;
  if (o < 64)        v = wq[(h * 64 + o) * 1024 + col];
  else if (o < 128)  v = wk[(h * 64 + o - 64) * 1024 + col];
  else if (o < 192)  v = wv[(h * 64 + o - 128) * 1024 + col];
  else if (o == 192) v = lrw[h * 1024 + col];
  else               v = 0.f;
  Wcat[i] = f2bf(v);
  if (i < 4096) {
    int hh = i >> 8, oo = i & 255;
    float bv;
    if (oo < 64)        bv = wqb[hh * 64 + oo];
    else if (oo < 128)  bv = wkb[hh * 64 + oo - 64];
    else if (oo < 192)  bv = wvb[hh * 64 + oo - 128];
    else if (oo == 192) bv = lrb[hh];
    else                bv = 0.f;
    biasc[i] = bv;
  }
}

// ================= fused QKV producer + scan consumer ======================
// blocks 0..63   : scan chain (b,h); chunk nc gated on prog[b*32 + nc/4]==16
// blocks 64..2111: QKV 256x256 tile; id -> (w, b, h) w-major so tokens
//                  complete in scan order; publish prog[b*32+w] at end.
__global__ __launch_bounds__(512, 1) void qkv_scan(
    const unsigned short* __restrict__ A, const unsigned short* __restrict__ B,
    const float* __restrict__ bias, const float* __restrict__ tnw,
    const float* __restrict__ tnb, unsigned short* __restrict__ XQn,
    unsigned short* __restrict__ XKn, unsigned short* __restrict__ TGT,
    float* __restrict__ eta_buf, const float* __restrict__ W1,
    const float* __restrict__ b1, unsigned short* __restrict__ y,
    unsigned int* __restrict__ prog) {
  __shared__ __align__(16) char smem[102912];
  const int tid = threadIdx.x;
  const int lane = tid & 63, wid = tid >> 6;
  const int l15 = lane & 15, lg = lane >> 4;

  if (blockIdx.x >= 64) {
    // =================== PRODUCER: QKV GEMM tile ===================
    char* ldsc = smem;  // 96 KB (3 x 32KB slots)
    const int bid2 = blockIdx.x - 64;
    const int w = bid2 >> 6, rem = bid2 & 63, bb = rem >> 4, h = rem & 15;
    const int mprog = bb * 32 + w;
    const long m0 = (long)mprog * 256;
    const long n0 = (long)h * 256;
    const long K = 1024, ldab = 2048;

    const int wm = wid >> 2, wn = wid & 3;
    const int srow = wid * 16 + (lane >> 2);
    const int scol = ((lane & 3) * 16) ^ (((lane >> 3) & 3) << 4);
    const int sdst = wid * 1024;
    const char* Ab = (const char*)A;
    const char* Bb = (const char*)B;
    const int acol = (lg * 16) ^ (((l15 >> 1) & 3) << 4);
    const int aro = (wm * 128 + l15) * 64 + acol;
    const int bro = 16384 + (wn * 64 + l15) * 64 + acol;

#define STG_A(tt, hh, bbu)                                                    \
  gload_lds16(Ab + (size_t)(m0 + (hh) * 128 + srow) * ldab +                  \
                  (size_t)(tt) * 64 + scol,                                   \
              ldsc + (bbu) * 32768 + (hh) * 8192 + sdst)
#define STG_B(tt, hh, bbu)                                                    \
  gload_lds16(Bb + (size_t)(n0 + (hh) * 128 + srow) * ldab +                  \
                  (size_t)(tt) * 64 + scol,                                   \
              ldsc + (bbu) * 32768 + 16384 + (hh) * 8192 + sdst)

    f32x4 acc[8][4];
#pragma unroll
    for (int m = 0; m < 8; ++m)
#pragma unroll
      for (int n = 0; n < 4; ++n) acc[m][n] = (f32x4){0.f, 0.f, 0.f, 0.f};

    const int NT = (int)(K >> 5);
    STG_A(0, 0, 0); STG_A(0, 1, 0); STG_B(0, 0, 0); STG_B(0, 1, 0);
    STG_A(1, 0, 1); STG_A(1, 1, 1); STG_B(1, 0, 1); STG_B(1, 1, 1);
    asm volatile("s_waitcnt vmcnt(4)" ::: "memory");
    bar_nowait();

    int buf = 0, sb = 2;
#pragma unroll 1
    for (int t = 0; t < NT; ++t) {
      if (t + 2 < NT) {
        STG_A(t + 2, 0, sb); STG_A(t + 2, 1, sb);
        STG_B(t + 2, 0, sb); STG_B(t + 2, 1, sb);
      }
      const char* ab = ldsc + buf * 32768 + aro;
      const char* bb2 = ldsc + buf * 32768 + bro;
      short8 av[8], bv[4];
#pragma unroll
      for (int i = 0; i < 8; ++i) av[i] = *(const short8*)(ab + i * 1024);
#pragma unroll
      for (int nf = 0; nf < 4; ++nf) bv[nf] = *(const short8*)(bb2 + nf * 1024);
      __builtin_amdgcn_s_setprio(1);
#pragma unroll
      for (int i = 0; i < 8; ++i)
#pragma unroll
        for (int nf = 0; nf < 4; ++nf)
          acc[i][nf] = __builtin_amdgcn_mfma_f32_16x16x32_bf16(
              av[i], bv[nf], acc[i][nf], 0, 0, 0);
      __builtin_amdgcn_s_setprio(0);
      if (t < NT - 2)
        asm volatile("s_waitcnt vmcnt(4)" ::: "memory");
      else
        asm volatile("s_waitcnt vmcnt(0)" ::: "memory");  // tail: all landed
      bar_nowait();
      buf = (buf == 2) ? 0 : buf + 1;
      sb = (sb == 2) ? 0 : sb + 1;
    }
#undef STG_A
#undef STG_B

    // ---- fused stage2 epilogue ----
    float bcol[4], twv[4], tbv[4];
#pragma unroll
    for (int nf = 0; nf < 4; ++nf) {
      bcol[nf] = bias[n0 + wn * 64 + nf * 16 + l15];
      twv[nf] = tnw[h * 64 + nf * 16 + l15];
      tbv[nf] = tnb[h * 64 + nf * 16 + l15];
    }
    __syncthreads();
    unsigned short* kn_s = (unsigned short*)smem;  // [256][72]

    if (wn == 0) {
#pragma unroll
      for (int mf = 0; mf < 8; ++mf)
#pragma unroll
        for (int j = 0; j < 4; ++j) {
          float v[4], s2 = 0.f;
#pragma unroll
          for (int nf = 0; nf < 4; ++nf) {
            v[nf] = acc[mf][nf][j] + bcol[nf];
            s2 += v[nf] * v[nf];
          }
          s2 = dpp16_sum(s2);
          float rn = 1.f / fmaxf(sqrtf(s2), 1e-12f);
          size_t tt = (size_t)(m0 + wm * 128 + mf * 16 + lg * 4 + j);
#pragma unroll
          for (int nf = 0; nf < 4; ++nf)
            XQn[tt * 1024 + h * 64 + nf * 16 + l15] = f2bf(v[nf] * rn);
        }
    } else if (wn == 1) {
#pragma unroll
      for (int mf = 0; mf < 8; ++mf)
#pragma unroll
        for (int j = 0; j < 4; ++j) {
          float v[4], s2 = 0.f;
#pragma unroll
          for (int nf = 0; nf < 4; ++nf) {
            v[nf] = acc[mf][nf][j] + bcol[nf];
            s2 += v[nf] * v[nf];
          }
          s2 = dpp16_sum(s2);
          float rn = 1.f / fmaxf(sqrtf(s2), 1e-12f);
          size_t tt = (size_t)(m0 + wm * 128 + mf * 16 + lg * 4 + j);
          int lr_ = wm * 128 + mf * 16 + lg * 4 + j;
#pragma unroll
          for (int nf = 0; nf < 4; ++nf) {
            unsigned short kb = f2bf(v[nf] * rn);
            XKn[tt * 1024 + h * 64 + nf * 16 + l15] = kb;
            kn_s[lr_ * 72 + nf * 16 + l15] = kb;
          }
        }
    }
    __syncthreads();
    if (wn == 2) {
#pragma unroll
      for (int mf = 0; mf < 8; ++mf)
#pragma unroll
        for (int j = 0; j < 4; ++j) {
          int lr_ = wm * 128 + mf * 16 + lg * 4 + j;
          float dv[4], s1 = 0.f, s2 = 0.f;
#pragma unroll
          for (int nf = 0; nf < 4; ++nf) {
            float kn = bf2f(kn_s[lr_ * 72 + nf * 16 + l15]);
            dv[nf] = acc[mf][nf][j] + bcol[nf] - kn;
            s1 += dv[nf];
            s2 += dv[nf] * dv[nf];
          }
          s1 = dpp16_sum(s1);
          s2 = dpp16_sum(s2);
          float mu = s1 * 0.015625f;
          float var1 = fmaxf(s2 - 64.f * mu * mu, 0.f) * (1.f / 63.f);
          float rs = 1.f / (sqrtf(var1) + 1e-5f);
          size_t tt = (size_t)(m0 + wm * 128 + mf * 16 + lg * 4 + j);
#pragma unroll
          for (int nf = 0; nf < 4; ++nf)
            TGT[tt * 1024 + h * 64 + nf * 16 + l15] =
                f2bf(twv[nf] * ((dv[nf] - mu) * rs) + tbv[nf]);
        }
    } else if (wn == 3 && l15 == 0) {
#pragma unroll
      for (int mf = 0; mf < 8; ++mf)
#pragma unroll
        for (int j = 0; j < 4; ++j) {
          size_t tt = (size_t)(m0 + wm * 128 + mf * 16 + lg * 4 + j);
          float lgt = acc[mf][0][j] + bcol[0];
          float sig = 1.f / (1.f + expf(-lgt));
          eta_buf[((tt >> 13) * 16 + h) * 8192 + (tt & 8191)] =
              sig * (1.f / 4096.f);
        }
    }
    // ---- publish ----
    asm volatile("s_waitcnt vmcnt(0)" ::: "memory");
    __syncthreads();
    if (tid == 0) {
      __threadfence();
      __hip_atomic_fetch_add(&prog[mprog], 1u, __ATOMIC_RELEASE,
                             __HIP_MEMORY_SCOPE_AGENT);
    }
    return;
  }

  // =================== CONSUMER: scan chain ===================
  unsigned short* xq_s = (unsigned short*)(smem);           // [2][4608]
  unsigned short* tg_s = (unsigned short*)(smem + 18432);
  unsigned short* xk_s = (unsigned short*)(smem + 36864);
  unsigned short* gc_s = (unsigned short*)(smem + 55296);
  unsigned short* gradT = (unsigned short*)(smem + 64512);
  unsigned short* xkTe = (unsigned short*)(smem + 73728);
  unsigned short* WT_b = (unsigned short*)(smem + 82944);   // [2][4608]
  float* eta_s = (float*)(smem + 101376);                   // [2][64]
  float* bpart = (float*)(smem + 101888);                   // [4][64]

  const int bh = blockIdx.x;
  const int b = bh >> 4, h = bh & 15;
  const bool isA = wid < 4;
  const int q = wid & 3;
  const size_t tokb = (size_t)b * 8192;
  const int col0 = h * 64;
  const int rr_ = q * 16 + (lane >> 3);
  const int c8_ = (lane & 7) * 8;

  short8 pA0[2], pA1[2], pB0[2];
  float peta = 0.f;
  float bstv[4], gwv[4], gbv[4];
  f32x4 Wreg[4];

  if (isA) {
#pragma unroll
    for (int n = 0; n < 4; ++n) {
      int e = n * 16 + l15;
      bstv[n] = b1[h * 64 + e];
      gwv[n] = tnw[h * 64 + e];
      gbv[n] = tnb[h * 64 + e];
    }
  } else {
#pragma unroll
    for (int n = 0; n < 4; ++n)
#pragma unroll
      for (int jj = 0; jj < 4; ++jj) {
        int d = q * 16 + lg * 4 + jj, e = n * 16 + l15;
        float w2 = W1[h * 4096 + d * 64 + e];
        Wreg[n][jj] = w2;
        WT_b[e * 72 + d] = f2bf(w2);
      }
  }
  if (tid == 0) {
    while (__hip_atomic_load(&prog[b << 5], __ATOMIC_ACQUIRE,
                             __HIP_MEMORY_SCOPE_AGENT) < 16u)
      __builtin_amdgcn_s_sleep(16);
  }
  __syncthreads();

  if (isA) {
#pragma unroll
    for (int j = 0; j < 2; ++j) {
      size_t g = (tokb + rr_ + j * 8) * 1024 + col0 + c8_;
      pA0[j] = *(const short8*)&XQn[g];
      pA1[j] = *(const short8*)&TGT[g];
    }
#pragma unroll
    for (int j = 0; j < 2; ++j) {
      int rr = rr_ + j * 8;
      *(short8*)&xq_s[rr * 72 + c8_] = pA0[j];
      *(short8*)&tg_s[rr * 72 + c8_] = pA1[j];
    }
#pragma unroll
    for (int j = 0; j < 2; ++j) {
      size_t g = (tokb + 64 + rr_ + j * 8) * 1024 + col0 + c8_;
      pA0[j] = *(const short8*)&XQn[g];
      pA1[j] = *(const short8*)&TGT[g];
    }
  } else {
#pragma unroll
    for (int j = 0; j < 2; ++j)
      pB0[j] = *(const short8*)&XKn[(tokb + rr_ + j * 8) * 1024 + col0 + c8_];
#pragma unroll
    for (int j = 0; j < 2; ++j)
      *(short8*)&xk_s[(rr_ + j * 8) * 72 + c8_] = pB0[j];
#pragma unroll
    for (int j = 0; j < 2; ++j)
      pB0[j] = *(const short8*)&XKn[(tokb + 64 + rr_ + j * 8) * 1024 + col0 + c8_];
    if (wid == 4) {
      eta_s[lane] = eta_buf[(size_t)bh * 8192 + lane];
      peta = eta_buf[(size_t)bh * 8192 + 64 + lane];
    }
  }
  __syncthreads();

  for (int nc = 0; nc < 128; ++nc) {
    const int p = nc & 1;
    if (nc + 2 < 128 && ((nc + 2) & 3) == 0) {
      if (tid == 0) {
        while (__hip_atomic_load(&prog[(b << 5) + ((nc + 2) >> 2)],
                                 __ATOMIC_ACQUIRE,
                                 __HIP_MEMORY_SCOPE_AGENT) < 16u)
          __builtin_amdgcn_s_sleep(16);
      }
      bar_nowait();
    }
    const unsigned short* WTc = WT_b + p * 4608;
    unsigned short* WTn = WT_b + (p ^ 1) * 4608;
    unsigned short* xqp = xq_s + p * 4608;
    unsigned short* tgp = tg_s + p * 4608;
    unsigned short* xkp = xk_s + p * 4608;
    float* etp = eta_s + p * 64;

    // ================= phase 1 =================
    if (isA) {
      if (nc) {
#pragma unroll
        for (int n = 0; n < 4; ++n) {
          int e = n * 16 + l15;
          bstv[n] -= bpart[e] + bpart[64 + e] + bpart[128 + e] + bpart[192 + e];
        }
      }
      if (nc + 1 < 128) {
        unsigned short* xqn = xq_s + (p ^ 1) * 4608;
        unsigned short* tgn = tg_s + (p ^ 1) * 4608;
#pragma unroll
        for (int j = 0; j < 2; ++j) {
          int rr = rr_ + j * 8;
          *(short8*)&xqn[rr * 72 + c8_] = pA0[j];
          *(short8*)&tgn[rr * 72 + c8_] = pA1[j];
        }
      }
      if (nc + 2 < 128) {
#pragma unroll
        for (int j = 0; j < 2; ++j) {
          size_t g = (tokb + (nc + 2) * 64 + rr_ + j * 8) * 1024 + col0 + c8_;
          pA0[j] = *(const short8*)&XQn[g];
          pA1[j] = *(const short8*)&TGT[g];
        }
      }
      f32x4 accZ[4];
#pragma unroll
      for (int n = 0; n < 4; ++n)
        accZ[n] = (f32x4){bstv[n], bstv[n], bstv[n], bstv[n]};
      __builtin_amdgcn_s_setprio(1);
#pragma unroll
      for (int kk = 0; kk < 2; ++kk) {
        const int ko = kk * 32 + lg * 8;
        short8 a_xk = *(const short8*)&xkp[(q * 16 + l15) * 72 + ko];
#pragma unroll
        for (int n = 0; n < 4; ++n) {
          short8 b_w = *(const short8*)&WTc[(n * 16 + l15) * 72 + ko];
          accZ[n] = __builtin_amdgcn_mfma_f32_16x16x32_bf16(a_xk, b_w, accZ[n], 0, 0, 0);
        }
      }
      __builtin_amdgcn_s_setprio(0);
      float grv[4][4];
#pragma unroll
      for (int j = 0; j < 4; ++j) {
        const int r = q * 16 + lg * 4 + j;
        float z[4], s1 = 0.f, s2 = 0.f;
#pragma unroll
        for (int n = 0; n < 4; ++n) {
          z[n] = accZ[n][j];
          s1 += z[n];
          s2 += z[n] * z[n];
        }
        s1 = dpp16_sum(s1);
        s2 = dpp16_sum(s2);
        float mu = s1 * 0.015625f;
        float var = s2 * 0.015625f - mu * mu;
        float rstd = rsqrtf(var + 1e-6f);
        float xh[4], gx[4], s3 = 0.f, s4 = 0.f;
#pragma unroll
        for (int n = 0; n < 4; ++n) {
          xh[n] = (z[n] - mu) * rstd;
          float tg = bf2f(tgp[r * 72 + n * 16 + l15]);
          float go = gwv[n] * xh[n] + gbv[n] - tg;
          gx[n] = go * gwv[n];
          s3 += gx[n];
          s4 += gx[n] * xh[n];
        }
        s3 = dpp16_sum(s3);
        s4 = dpp16_sum(s4);
#pragma unroll
        for (int n = 0; n < 4; ++n)
          grv[n][j] = (64.f * gx[n] - s3 - xh[n] * s4) * rstd * 0.015625f;
      }
#pragma unroll
      for (int n = 0; n < 4; ++n) {
        us4 pk = {f2bf(grv[n][0]), f2bf(grv[n][1]), f2bf(grv[n][2]),
                  f2bf(grv[n][3])};
        *(us4*)&gradT[(n * 16 + l15) * 72 + q * 16 + lg * 4] = pk;
      }
    } else {
      if (nc + 1 < 128) {
        unsigned short* xkn = xk_s + (p ^ 1) * 4608;
#pragma unroll
        for (int j = 0; j < 2; ++j)
          *(short8*)&xkn[(rr_ + j * 8) * 72 + c8_] = pB0[j];
        if (wid == 4) eta_s[(p ^ 1) * 64 + lane] = peta;
      }
      if (nc + 2 < 128) {
#pragma unroll
        for (int j = 0; j < 2; ++j)
          pB0[j] = *(const short8*)
              &XKn[(tokb + (nc + 2) * 64 + rr_ + j * 8) * 1024 + col0 + c8_];
        if (wid == 4) peta = eta_buf[(size_t)bh * 8192 + (nc + 2) * 64 + lane];
      }
#pragma unroll
      for (int it = 0; it < 4; ++it) {
        int c0 = q * 16 + it * 4;
        us4 pk;
#pragma unroll
        for (int u = 0; u < 4; ++u)
          pk[u] = f2bf(-etp[c0 + u] * bf2f(xkp[(c0 + u) * 72 + lane]));
        *(us4*)&xkTe[lane * 72 + c0] = pk;
      }
      f32x4 accA[4];
#pragma unroll
      for (int n = 0; n < 4; ++n) accA[n] = (f32x4){0.f, 0.f, 0.f, 0.f};
      __builtin_amdgcn_s_setprio(1);
#pragma unroll
      for (int kk = 0; kk < 2; ++kk) {
        const int ko = kk * 32 + lg * 8;
        short8 a_xq = *(const short8*)&xqp[(q * 16 + l15) * 72 + ko];
#pragma unroll
        for (int n = 0; n < 4; ++n) {
          short8 b_k = *(const short8*)&xkp[(n * 16 + l15) * 72 + ko];
          accA[n] = __builtin_amdgcn_mfma_f32_16x16x32_bf16(a_xq, b_k, accA[n], 0, 0, 0);
        }
      }
      __builtin_amdgcn_s_setprio(0);
#pragma unroll
      for (int j = 0; j < 4; ++j) {
        const int r = q * 16 + lg * 4 + j;
#pragma unroll
        for (int n = 0; n < 4; ++n) {
          int cj = n * 16 + l15;
          float v = (cj <= r) ? (-etp[cj] * (1.f + accA[n][j])) : 0.f;
          gc_s[r * 72 + cj] = f2bf(v);
        }
      }
    }
    barrier_fast();  // X

    // ================= phase 2 =================
    if (isA) {
      f32x4 accZb[4];
#pragma unroll
      for (int n = 0; n < 4; ++n)
        accZb[n] = (f32x4){bstv[n], bstv[n], bstv[n], bstv[n]};
      __builtin_amdgcn_s_setprio(1);
#pragma unroll
      for (int kk = 0; kk < 2; ++kk) {
        const int ko = kk * 32 + lg * 8;
        short8 a_xq = *(const short8*)&xqp[(q * 16 + l15) * 72 + ko];
        short8 a_gc = *(const short8*)&gc_s[(q * 16 + l15) * 72 + ko];
#pragma unroll
        for (int n = 0; n < 4; ++n) {
          short8 b_w = *(const short8*)&WTc[(n * 16 + l15) * 72 + ko];
          short8 b_g = *(const short8*)&gradT[(n * 16 + l15) * 72 + ko];
          accZb[n] = __builtin_amdgcn_mfma_f32_16x16x32_bf16(a_xq, b_w, accZb[n], 0, 0, 0);
          accZb[n] = __builtin_amdgcn_mfma_f32_16x16x32_bf16(a_gc, b_g, accZb[n], 0, 0, 0);
        }
      }
      __builtin_amdgcn_s_setprio(0);
#pragma unroll
      for (int j = 0; j < 4; ++j) {
        const int r = q * 16 + lg * 4 + j;
        float z[4], s1 = 0.f, s2 = 0.f;
#pragma unroll
        for (int n = 0; n < 4; ++n) {
          z[n] = accZb[n][j];
          s1 += z[n];
          s2 += z[n] * z[n];
        }
        s1 = dpp16_sum(s1);
        s2 = dpp16_sum(s2);
        float mu = s1 * 0.015625f;
        float var = s2 * 0.015625f - mu * mu;
        float rstd = rsqrtf(var + 1e-6f);
        size_t gbase = (tokb + nc * 64 + r) * 1024 + col0;
#pragma unroll
        for (int n = 0; n < 4; ++n) {
          int e = n * 16 + l15;
          float ov = bf2f(xqp[r * 72 + e]) + gwv[n] * ((z[n] - mu) * rstd) + gbv[n];
          y[gbase + e] = (unsigned short)(cvtpk(ov, ov) & 0xffffu);
        }
      }
    } else {
      short8 a_ke[2], b_g[2][4];
#pragma unroll
      for (int kk = 0; kk < 2; ++kk) {
        const int ko = kk * 32 + lg * 8;
        a_ke[kk] = *(const short8*)&xkTe[(q * 16 + l15) * 72 + ko];
#pragma unroll
        for (int n = 0; n < 4; ++n)
          b_g[kk][n] = *(const short8*)&gradT[(n * 16 + l15) * 72 + ko];
      }
      f32x4 accW[4];
#pragma unroll
      for (int n = 0; n < 4; ++n) accW[n] = Wreg[n];
      __builtin_amdgcn_s_setprio(1);
#pragma unroll
      for (int kk = 0; kk < 2; ++kk)
#pragma unroll
        for (int n = 0; n < 4; ++n)
          accW[n] = __builtin_amdgcn_mfma_f32_16x16x32_bf16(a_ke[kk], b_g[kk][n],
                                                            accW[n], 0, 0, 0);
      __builtin_amdgcn_s_setprio(0);
#pragma unroll
      for (int n = 0; n < 4; ++n) {
        Wreg[n] = accW[n];
        us4 pk = {f2bf(accW[n][0]), f2bf(accW[n][1]), f2bf(accW[n][2]),
                  f2bf(accW[n][3])};
        *(us4*)&WTn[(n * 16 + l15) * 72 + q * 16 + lg * 4] = pk;
      }
      {
        float s = 0.f;
#pragma unroll
        for (int it = 0; it < 4; ++it) {
          us4 gv = *(const us4*)&gradT[lane * 72 + q * 16 + it * 4];
#pragma unroll
          for (int u = 0; u < 4; ++u)
            s += etp[q * 16 + it * 4 + u] * bf2f(gv[u]);
        }
        bpart[q * 64 + lane] = s;
      }
    }
    barrier_fast();  // Y
  }
}

// ========== fused postnorm + out-GEMM (r13 consumer, standalone) ===========
// 512 blocks: i -> (mtile = i>>2, ntile = i&3). Stats pass over 256 y-rows,
// then 3-slot GEMM with normalize-on-stage A (bf16 y) + gload_lds B (wo).
__global__ __launch_bounds__(512, 1) void out_fused(
    const unsigned short* __restrict__ y, const unsigned short* __restrict__ wo_bf,
    const float* __restrict__ wob, const float* __restrict__ pnw,
    const float* __restrict__ pnb, float* __restrict__ out) {
  __shared__ __align__(16) char smem[108544];
  char* ldsc = smem;                          // 3 x 32KB GEMM slots
  float* mu_s = (float*)(smem + 98304);       // [256]
  float* rs_s = (float*)(smem + 99328);       // [256]
  float* pnw_s = (float*)(smem + 100352);     // [1024]
  float* pnb_s = (float*)(smem + 104448);     // [1024]

  const int tid = threadIdx.x;
  const int lane = tid & 63, wid = tid >> 6;
  const int l15 = lane & 15, lg = lane >> 4;
  const int wm = wid >> 2, wn = wid & 3;
  const int srow = wid * 16 + (lane >> 2);
  const int scol = ((lane & 3) * 16) ^ (((lane >> 3) & 3) << 4);
  const int sdst = wid * 1024;
  const int acol = (lg * 16) ^ (((l15 >> 1) & 3) << 4);
  const int aro = (wm * 128 + l15) * 64 + acol;
  const int bro = 16384 + (wn * 64 + l15) * 64 + acol;

  const long m0 = (long)(blockIdx.x >> 2) * 256;
  const long n0 = (long)(blockIdx.x & 3) * 256;

  if (tid < 256) *(float4*)&pnw_s[tid * 4] = *(const float4*)&pnw[tid * 4];
  else { int t2 = tid - 256; *(float4*)&pnb_s[t2 * 4] = *(const float4*)&pnb[t2 * 4]; }

  // row stats (bf16 y)
  for (int rr = 0; rr < 32; ++rr) {
    int r = wid * 32 + rr;
    const unsigned short* row = y + (size_t)(m0 + r) * 1024;
    float s1 = 0.f, s2 = 0.f;
#pragma unroll
    for (int k = 0; k < 4; ++k) {
      us4 v4 = *(const us4*)&row[k * 256 + lane * 4];
#pragma unroll
      for (int u = 0; u < 4; ++u) {
        float f = bf2f(v4[u]);
        s1 += f;
        s2 += f * f;
      }
    }
#pragma unroll
    for (int o2 = 1; o2 < 64; o2 <<= 1) {
      s1 += __shfl_xor(s1, o2);
      s2 += __shfl_xor(s2, o2);
    }
    if (lane == 0) {
      float mu = s1 * (1.f / 1024.f);
      float var = s2 * (1.f / 1024.f) - mu * mu;
      mu_s[r] = mu;
      rs_s[r] = rsqrtf(var + 1e-6f);
    }
  }
  __syncthreads();

  auto stageA = [&](int tt, int sl) {
    int r = tid >> 1, half = tid & 1;
    const unsigned short* ysrc = y + (size_t)(m0 + r) * 1024 + tt * 32 + half * 16;
    us4 h0 = *(const us4*)(ysrc);
    us4 h1 = *(const us4*)(ysrc + 4);
    us4 h2 = *(const us4*)(ysrc + 8);
    us4 h3 = *(const us4*)(ysrc + 12);
    float mu = mu_s[r], rs = rs_s[r];
    int c0 = tt * 32 + half * 16;
    __align__(16) unsigned short o[16];
    unsigned short vin[16] = {h0[0], h0[1], h0[2], h0[3], h1[0], h1[1], h1[2],
                              h1[3], h2[0], h2[1], h2[2], h2[3], h3[0], h3[1],
                              h3[2], h3[3]};
#pragma unroll
    for (int u = 0; u < 16; ++u)
      o[u] = f2bf(pnw_s[c0 + u] * ((bf2f(vin[u]) - mu) * rs) + pnb_s[c0 + u]);
    int key = ((r >> 1) & 3) << 4;
    char* base = ldsc + sl * 32768 + r * 64;
    *(short8*)(base + ((half * 32) ^ key)) = *(short8*)&o[0];
    *(short8*)(base + ((half * 32 + 16) ^ key)) = *(short8*)&o[8];
  };
  auto stgB = [&](int tt, int sl) {
    gload_lds16((const char*)wo_bf + (size_t)(n0 + srow) * 2048 +
                    (size_t)tt * 64 + scol,
                ldsc + sl * 32768 + 16384 + sdst);
    gload_lds16((const char*)wo_bf + (size_t)(n0 + 128 + srow) * 2048 +
                    (size_t)tt * 64 + scol,
                ldsc + sl * 32768 + 16384 + 8192 + sdst);
  };

  f32x4 acc[8][4];
#pragma unroll
  for (int m = 0; m < 8; ++m)
#pragma unroll
    for (int n = 0; n < 4; ++n) acc[m][n] = (f32x4){0.f, 0.f, 0.f, 0.f};

  stgB(0, 0); stgB(1, 1);
  stageA(0, 0); stageA(1, 1);
  asm volatile("s_waitcnt vmcnt(2)" ::: "memory");
  barrier_fast();

#pragma unroll 1
  for (int t = 0; t < 32; ++t) {
    const int buf = t % 3, sb = (t + 2) % 3;
    if (t + 2 < 32) { stgB(t + 2, sb); stageA(t + 2, sb); }
    const char* ab = ldsc + buf * 32768 + aro;
    const char* bb2 = ldsc + buf * 32768 + bro;
    short8 av[8], bv[4];
#pragma unroll
    for (int ii = 0; ii < 8; ++ii) av[ii] = *(const short8*)(ab + ii * 1024);
#pragma unroll
    for (int nf = 0; nf < 4; ++nf) bv[nf] = *(const short8*)(bb2 + nf * 1024);
    __builtin_amdgcn_s_setprio(1);
#pragma unroll
    for (int ii = 0; ii < 8; ++ii)
#pragma unroll
      for (int nf = 0; nf < 4; ++nf)
        acc[ii][nf] = __builtin_amdgcn_mfma_f32_16x16x32_bf16(
            av[ii], bv[nf], acc[ii][nf], 0, 0, 0);
    __builtin_amdgcn_s_setprio(0);
    if (t + 2 < 32)
      asm volatile("s_waitcnt vmcnt(2)" ::: "memory");
    else
      asm volatile("s_waitcnt vmcnt(0)" ::: "memory");
    barrier_fast();
  }

#pragma unroll
  for (int mf = 0; mf < 8; ++mf) {
    long r0 = m0 + wm * 128 + mf * 16 + lg * 4;
#pragma unroll
    for (int nf = 0; nf < 4; ++nf) {
      long c = n0 + wn * 64 + nf * 16 + l15;
      float bvv = wob[c];
#pragma unroll
      for (int j = 0; j < 4; ++j)
        out[(r0 + j) * 1024 + c] = acc[mf][nf][j] + bvv;
    }
  }
}

// ---------------------------------------------------------------------------
extern "C" void kernel_launch(void* const* d_in, const int* in_sizes, int n_in,
                              void* d_out, int out_size, void* d_ws,
                              size_t ws_size, hipStream_t stream) {
  const float* hs  = (const float*)d_in[0];
  const float* wqw = (const float*)d_in[1];
  const float* wqb = (const float*)d_in[2];
  const float* wkw = (const float*)d_in[3];
  const float* wkb = (const float*)d_in[4];
  const float* wvw = (const float*)d_in[5];
  const float* wvb = (const float*)d_in[6];
  const float* wow = (const float*)d_in[7];
  const float* wob = (const float*)d_in[8];
  const float* tnw = (const float*)d_in[9];
  const float* tnb = (const float*)d_in[10];
  const float* lrw = (const float*)d_in[11];
  const float* lrb = (const float*)d_in[12];
  const float* W1  = (const float*)d_in[13];
  const float* b1  = (const float*)d_in[14];
  const float* pnw = (const float*)d_in[15];
  const float* pnb = (const float*)d_in[16];

  // layout: XQ(64M) | XK(64M) | TGT(64M) | eta(2M) | wo(2M) | prog(4K) |
  //         hs_bf(64M) | Wcat(8M) | biasc(16K) | ybf(64M)
  const size_t OFF_XQ    = 0;
  const size_t OFF_XK    = 67108864;
  const size_t OFF_TGT   = 134217728;
  const size_t OFF_ETA   = 201326592;
  const size_t OFF_WOBF  = 203423744;
  const size_t OFF_PROG  = 205520896;
  const size_t OFF_HSBF  = 205524992;
  const size_t OFF_WCAT  = OFF_HSBF + 67108864;
  const size_t OFF_BIASC = OFF_WCAT + 8388608;
  const size_t OFF_YBF   = OFF_BIASC + 16384;
  const size_t NEEDED    = OFF_YBF + 67108864;
  if (ws_size < NEEDED) return;

  char* ws = (char*)d_ws;
  unsigned short* XQn   = (unsigned short*)(ws + OFF_XQ);
  unsigned short* XKn   = (unsigned short*)(ws + OFF_XK);
  unsigned short* TGT   = (unsigned short*)(ws + OFF_TGT);
  float* eta_buf        = (float*)(ws + OFF_ETA);
  unsigned short* wo_bf = (unsigned short*)(ws + OFF_WOBF);
  unsigned int* prog    = (unsigned int*)(ws + OFF_PROG);
  unsigned short* hs_bf = (unsigned short*)(ws + OFF_HSBF);
  unsigned short* Wcat  = (unsigned short*)(ws + OFF_WCAT);
  float* biasc          = (float*)(ws + OFF_BIASC);
  unsigned short* ybf   = (unsigned short*)(ws + OFF_YBF);

  cvt_f32_bf16<<<32768, 256, 0, stream>>>(hs, hs_bf, 33554432L);
  build_wcat<<<16384, 256, 0, stream>>>(wqw, wkw, wvw, lrw, wqb, wkb, wvb, lrb,
                                        Wcat, biasc);
  cvt_f32_bf16<<<1024, 256, 0, stream>>>(wow, wo_bf, 1048576L);
  hipMemsetAsync(prog, 0, 4096, stream);
  qkv_scan<<<2112, 512, 0, stream>>>(hs_bf, Wcat, biasc, tnw, tnb,
                                     XQn, XKn, TGT, eta_buf, W1, b1, ybf, prog);
  out_fused<<<512, 512, 0, stream>>>(ybf, wo_bf, wob, pnw, pnb, (float*)d_out);
}

// Round 18
// 776.933 us; speedup vs baseline: 1.0640x; 1.0640x over previous
//
#include <hip/hip_runtime.h>

// ---------------------------------------------------------------------------
// TTT layer forward: B=4, L=8192, D=1024, H=16, HD=64, C=64, NC=128
// FINAL (r15 config): fused {QKV GEMM producer || TTT scan consumer} with
// release/acquire tile gating, bf16 y, tail-fixed 3-slot GEMM loops,
// postnorm + output GEMM.   1508 us (r1 baseline) -> 777 us.
// ---------------------------------------------------------------------------

typedef __attribute__((ext_vector_type(8))) short short8;
typedef __attribute__((ext_vector_type(4))) float f32x4;
typedef __attribute__((ext_vector_type(4))) unsigned short us4;

__device__ __forceinline__ float bf2f(unsigned short s) {
  union { unsigned int u; float f; } c;
  c.u = ((unsigned int)s) << 16;
  return c.f;
}
__device__ __forceinline__ unsigned short f2bf(float f) {
  union { float f; unsigned int u; } c;
  c.f = f;
  unsigned int u = c.u;
  return (unsigned short)((u + 0x7FFFu + ((u >> 16) & 1u)) >> 16);
}
__device__ __forceinline__ unsigned cvtpk(float lo, float hi) {
  unsigned r;
  asm("v_cvt_pk_bf16_f32 %0, %1, %2" : "=v"(r) : "v"(lo), "v"(hi));
  return r;
}

__device__ __forceinline__ void gload_lds16(const void* g, void* l) {
  __builtin_amdgcn_global_load_lds(
      (const __attribute__((address_space(1))) unsigned int*)g,
      (__attribute__((address_space(3))) unsigned int*)l, 16, 0, 0);
}

__device__ __forceinline__ float dpp16_sum(float x) {
  int v = __float_as_int(x);
  x += __int_as_float(__builtin_amdgcn_update_dpp(v, v, 0xB1, 0xF, 0xF, true));
  v = __float_as_int(x);
  x += __int_as_float(__builtin_amdgcn_update_dpp(v, v, 0x4E, 0xF, 0xF, true));
  v = __float_as_int(x);
  x += __int_as_float(__builtin_amdgcn_update_dpp(v, v, 0x141, 0xF, 0xF, true));
  v = __float_as_int(x);
  x += __int_as_float(__builtin_amdgcn_update_dpp(v, v, 0x140, 0xF, 0xF, true));
  return x;
}

__device__ __forceinline__ void barrier_fast() {
  __builtin_amdgcn_sched_barrier(0);
  asm volatile("s_waitcnt lgkmcnt(0)" ::: "memory");
  __builtin_amdgcn_s_barrier();
  asm volatile("" ::: "memory");
  __builtin_amdgcn_sched_barrier(0);
}
__device__ __forceinline__ void bar_nowait() {
  __builtin_amdgcn_sched_barrier(0);
  asm volatile("" ::: "memory");
  __builtin_amdgcn_s_barrier();
  asm volatile("" ::: "memory");
  __builtin_amdgcn_sched_barrier(0);
}

// ---------------- conversion kernels ----------------
__global__ __launch_bounds__(256) void cvt_f32_bf16(
    const float* __restrict__ in, unsigned short* __restrict__ out, long n) {
  long i = ((long)blockIdx.x * 256 + threadIdx.x) * 4;
  if (i + 3 < n) {
    float4 v = *(const float4*)&in[i];
    us4 o = { f2bf(v.x), f2bf(v.y), f2bf(v.z), f2bf(v.w) };
    *(us4*)&out[i] = o;
  }
}

// Wcat (4096 rows): head h owns rows [h*256, h*256+256):
//   +0..63 wq rows, +64..127 wk, +128..191 wv, +192 lr_w, +193..255 zero
__global__ __launch_bounds__(256) void build_wcat(
    const float* __restrict__ wq, const float* __restrict__ wk,
    const float* __restrict__ wv, const float* __restrict__ lrw,
    const float* __restrict__ wqb, const float* __restrict__ wkb,
    const float* __restrict__ wvb, const float* __restrict__ lrb,
    unsigned short* __restrict__ Wcat, float* __restrict__ biasc) {
  int i = blockIdx.x * 256 + threadIdx.x;  // 0 .. 4096*1024-1
  int row = i >> 10, col = i & 1023;
  int h = row >> 8, o = row & 255;
  float v;
  if (o < 64)        v = wq[(h * 64 + o) * 1024 + col];
  else if (o < 128)  v = wk[(h * 64 + o - 64) * 1024 + col];
  else if (o < 192)  v = wv[(h * 64 + o - 128) * 1024 + col];
  else if (o == 192) v = lrw[h * 1024 + col];
  else               v = 0.f;
  Wcat[i] = f2bf(v);
  if (i < 4096) {
    int hh = i >> 8, oo = i & 255;
    float bv;
    if (oo < 64)        bv = wqb[hh * 64 + oo];
    else if (oo < 128)  bv = wkb[hh * 64 + oo - 64];
    else if (oo < 192)  bv = wvb[hh * 64 + oo - 128];
    else if (oo == 192) bv = lrb[hh];
    else                bv = 0.f;
    biasc[i] = bv;
  }
}

// ================= fused QKV producer + scan consumer ======================
// blocks 0..63   : scan chain (b,h); chunk nc gated on prog[b*32 + nc/4]==16
// blocks 64..2111: QKV 256x256 tile; id -> (w, b, h) w-major so tokens
//                  complete in scan order; publish prog[b*32+w] at end.
__global__ __launch_bounds__(512, 1) void qkv_scan(
    const unsigned short* __restrict__ A, const unsigned short* __restrict__ B,
    const float* __restrict__ bias, const float* __restrict__ tnw,
    const float* __restrict__ tnb, unsigned short* __restrict__ XQn,
    unsigned short* __restrict__ XKn, unsigned short* __restrict__ TGT,
    float* __restrict__ eta_buf, const float* __restrict__ W1,
    const float* __restrict__ b1, unsigned short* __restrict__ y,
    unsigned int* __restrict__ prog) {
  __shared__ __align__(16) char smem[102912];
  const int tid = threadIdx.x;
  const int lane = tid & 63, wid = tid >> 6;
  const int l15 = lane & 15, lg = lane >> 4;

  if (blockIdx.x >= 64) {
    // =================== PRODUCER: QKV GEMM tile ===================
    char* ldsc = smem;  // 96 KB (3 x 32KB slots)
    const int bid2 = blockIdx.x - 64;
    const int w = bid2 >> 6, rem = bid2 & 63, bb = rem >> 4, h = rem & 15;
    const int mprog = bb * 32 + w;
    const long m0 = (long)mprog * 256;
    const long n0 = (long)h * 256;
    const long K = 1024, ldab = 2048;

    const int wm = wid >> 2, wn = wid & 3;
    const int srow = wid * 16 + (lane >> 2);
    const int scol = ((lane & 3) * 16) ^ (((lane >> 3) & 3) << 4);
    const int sdst = wid * 1024;
    const char* Ab = (const char*)A;
    const char* Bb = (const char*)B;
    const int acol = (lg * 16) ^ (((l15 >> 1) & 3) << 4);
    const int aro = (wm * 128 + l15) * 64 + acol;
    const int bro = 16384 + (wn * 64 + l15) * 64 + acol;

#define STG_A(tt, hh, bbu)                                                    \
  gload_lds16(Ab + (size_t)(m0 + (hh) * 128 + srow) * ldab +                  \
                  (size_t)(tt) * 64 + scol,                                   \
              ldsc + (bbu) * 32768 + (hh) * 8192 + sdst)
#define STG_B(tt, hh, bbu)                                                    \
  gload_lds16(Bb + (size_t)(n0 + (hh) * 128 + srow) * ldab +                  \
                  (size_t)(tt) * 64 + scol,                                   \
              ldsc + (bbu) * 32768 + 16384 + (hh) * 8192 + sdst)

    f32x4 acc[8][4];
#pragma unroll
    for (int m = 0; m < 8; ++m)
#pragma unroll
      for (int n = 0; n < 4; ++n) acc[m][n] = (f32x4){0.f, 0.f, 0.f, 0.f};

    const int NT = (int)(K >> 5);
    STG_A(0, 0, 0); STG_A(0, 1, 0); STG_B(0, 0, 0); STG_B(0, 1, 0);
    STG_A(1, 0, 1); STG_A(1, 1, 1); STG_B(1, 0, 1); STG_B(1, 1, 1);
    asm volatile("s_waitcnt vmcnt(4)" ::: "memory");
    bar_nowait();

    int buf = 0, sb = 2;
#pragma unroll 1
    for (int t = 0; t < NT; ++t) {
      if (t + 2 < NT) {
        STG_A(t + 2, 0, sb); STG_A(t + 2, 1, sb);
        STG_B(t + 2, 0, sb); STG_B(t + 2, 1, sb);
      }
      const char* ab = ldsc + buf * 32768 + aro;
      const char* bb2 = ldsc + buf * 32768 + bro;
      short8 av[8], bv[4];
#pragma unroll
      for (int i = 0; i < 8; ++i) av[i] = *(const short8*)(ab + i * 1024);
#pragma unroll
      for (int nf = 0; nf < 4; ++nf) bv[nf] = *(const short8*)(bb2 + nf * 1024);
      __builtin_amdgcn_s_setprio(1);
#pragma unroll
      for (int i = 0; i < 8; ++i)
#pragma unroll
        for (int nf = 0; nf < 4; ++nf)
          acc[i][nf] = __builtin_amdgcn_mfma_f32_16x16x32_bf16(
              av[i], bv[nf], acc[i][nf], 0, 0, 0);
      __builtin_amdgcn_s_setprio(0);
      if (t < NT - 2)
        asm volatile("s_waitcnt vmcnt(4)" ::: "memory");
      else
        asm volatile("s_waitcnt vmcnt(0)" ::: "memory");  // tail: all landed
      bar_nowait();
      buf = (buf == 2) ? 0 : buf + 1;
      sb = (sb == 2) ? 0 : sb + 1;
    }
#undef STG_A
#undef STG_B

    // ---- fused stage2 epilogue ----
    float bcol[4], twv[4], tbv[4];
#pragma unroll
    for (int nf = 0; nf < 4; ++nf) {
      bcol[nf] = bias[n0 + wn * 64 + nf * 16 + l15];
      twv[nf] = tnw[h * 64 + nf * 16 + l15];
      tbv[nf] = tnb[h * 64 + nf * 16 + l15];
    }
    __syncthreads();
    unsigned short* kn_s = (unsigned short*)smem;  // [256][72]

    if (wn == 0) {
#pragma unroll
      for (int mf = 0; mf < 8; ++mf)
#pragma unroll
        for (int j = 0; j < 4; ++j) {
          float v[4], s2 = 0.f;
#pragma unroll
          for (int nf = 0; nf < 4; ++nf) {
            v[nf] = acc[mf][nf][j] + bcol[nf];
            s2 += v[nf] * v[nf];
          }
          s2 = dpp16_sum(s2);
          float rn = 1.f / fmaxf(sqrtf(s2), 1e-12f);
          size_t tt = (size_t)(m0 + wm * 128 + mf * 16 + lg * 4 + j);
#pragma unroll
          for (int nf = 0; nf < 4; ++nf)
            XQn[tt * 1024 + h * 64 + nf * 16 + l15] = f2bf(v[nf] * rn);
        }
    } else if (wn == 1) {
#pragma unroll
      for (int mf = 0; mf < 8; ++mf)
#pragma unroll
        for (int j = 0; j < 4; ++j) {
          float v[4], s2 = 0.f;
#pragma unroll
          for (int nf = 0; nf < 4; ++nf) {
            v[nf] = acc[mf][nf][j] + bcol[nf];
            s2 += v[nf] * v[nf];
          }
          s2 = dpp16_sum(s2);
          float rn = 1.f / fmaxf(sqrtf(s2), 1e-12f);
          size_t tt = (size_t)(m0 + wm * 128 + mf * 16 + lg * 4 + j);
          int lr_ = wm * 128 + mf * 16 + lg * 4 + j;
#pragma unroll
          for (int nf = 0; nf < 4; ++nf) {
            unsigned short kb = f2bf(v[nf] * rn);
            XKn[tt * 1024 + h * 64 + nf * 16 + l15] = kb;
            kn_s[lr_ * 72 + nf * 16 + l15] = kb;
          }
        }
    }
    __syncthreads();
    if (wn == 2) {
#pragma unroll
      for (int mf = 0; mf < 8; ++mf)
#pragma unroll
        for (int j = 0; j < 4; ++j) {
          int lr_ = wm * 128 + mf * 16 + lg * 4 + j;
          float dv[4], s1 = 0.f, s2 = 0.f;
#pragma unroll
          for (int nf = 0; nf < 4; ++nf) {
            float kn = bf2f(kn_s[lr_ * 72 + nf * 16 + l15]);
            dv[nf] = acc[mf][nf][j] + bcol[nf] - kn;
            s1 += dv[nf];
            s2 += dv[nf] * dv[nf];
          }
          s1 = dpp16_sum(s1);
          s2 = dpp16_sum(s2);
          float mu = s1 * 0.015625f;
          float var1 = fmaxf(s2 - 64.f * mu * mu, 0.f) * (1.f / 63.f);
          float rs = 1.f / (sqrtf(var1) + 1e-5f);
          size_t tt = (size_t)(m0 + wm * 128 + mf * 16 + lg * 4 + j);
#pragma unroll
          for (int nf = 0; nf < 4; ++nf)
            TGT[tt * 1024 + h * 64 + nf * 16 + l15] =
                f2bf(twv[nf] * ((dv[nf] - mu) * rs) + tbv[nf]);
        }
    } else if (wn == 3 && l15 == 0) {
#pragma unroll
      for (int mf = 0; mf < 8; ++mf)
#pragma unroll
        for (int j = 0; j < 4; ++j) {
          size_t tt = (size_t)(m0 + wm * 128 + mf * 16 + lg * 4 + j);
          float lgt = acc[mf][0][j] + bcol[0];
          float sig = 1.f / (1.f + expf(-lgt));
          eta_buf[((tt >> 13) * 16 + h) * 8192 + (tt & 8191)] =
              sig * (1.f / 4096.f);
        }
    }
    // ---- publish ----
    asm volatile("s_waitcnt vmcnt(0)" ::: "memory");
    __syncthreads();
    if (tid == 0) {
      __threadfence();
      __hip_atomic_fetch_add(&prog[mprog], 1u, __ATOMIC_RELEASE,
                             __HIP_MEMORY_SCOPE_AGENT);
    }
    return;
  }

  // =================== CONSUMER: scan chain ===================
  unsigned short* xq_s = (unsigned short*)(smem);           // [2][4608]
  unsigned short* tg_s = (unsigned short*)(smem + 18432);
  unsigned short* xk_s = (unsigned short*)(smem + 36864);
  unsigned short* gc_s = (unsigned short*)(smem + 55296);
  unsigned short* gradT = (unsigned short*)(smem + 64512);
  unsigned short* xkTe = (unsigned short*)(smem + 73728);
  unsigned short* WT_b = (unsigned short*)(smem + 82944);   // [2][4608]
  float* eta_s = (float*)(smem + 101376);                   // [2][64]
  float* bpart = (float*)(smem + 101888);                   // [4][64]

  const int bh = blockIdx.x;
  const int b = bh >> 4, h = bh & 15;
  const bool isA = wid < 4;
  const int q = wid & 3;
  const size_t tokb = (size_t)b * 8192;
  const int col0 = h * 64;
  const int rr_ = q * 16 + (lane >> 3);
  const int c8_ = (lane & 7) * 8;

  short8 pA0[2], pA1[2], pB0[2];
  float peta = 0.f;
  float bstv[4], gwv[4], gbv[4];
  f32x4 Wreg[4];

  if (isA) {
#pragma unroll
    for (int n = 0; n < 4; ++n) {
      int e = n * 16 + l15;
      bstv[n] = b1[h * 64 + e];
      gwv[n] = tnw[h * 64 + e];
      gbv[n] = tnb[h * 64 + e];
    }
  } else {
#pragma unroll
    for (int n = 0; n < 4; ++n)
#pragma unroll
      for (int jj = 0; jj < 4; ++jj) {
        int d = q * 16 + lg * 4 + jj, e = n * 16 + l15;
        float w2 = W1[h * 4096 + d * 64 + e];
        Wreg[n][jj] = w2;
        WT_b[e * 72 + d] = f2bf(w2);
      }
  }
  if (tid == 0) {
    while (__hip_atomic_load(&prog[b << 5], __ATOMIC_ACQUIRE,
                             __HIP_MEMORY_SCOPE_AGENT) < 16u)
      __builtin_amdgcn_s_sleep(16);
  }
  __syncthreads();

  if (isA) {
#pragma unroll
    for (int j = 0; j < 2; ++j) {
      size_t g = (tokb + rr_ + j * 8) * 1024 + col0 + c8_;
      pA0[j] = *(const short8*)&XQn[g];
      pA1[j] = *(const short8*)&TGT[g];
    }
#pragma unroll
    for (int j = 0; j < 2; ++j) {
      int rr = rr_ + j * 8;
      *(short8*)&xq_s[rr * 72 + c8_] = pA0[j];
      *(short8*)&tg_s[rr * 72 + c8_] = pA1[j];
    }
#pragma unroll
    for (int j = 0; j < 2; ++j) {
      size_t g = (tokb + 64 + rr_ + j * 8) * 1024 + col0 + c8_;
      pA0[j] = *(const short8*)&XQn[g];
      pA1[j] = *(const short8*)&TGT[g];
    }
  } else {
#pragma unroll
    for (int j = 0; j < 2; ++j)
      pB0[j] = *(const short8*)&XKn[(tokb + rr_ + j * 8) * 1024 + col0 + c8_];
#pragma unroll
    for (int j = 0; j < 2; ++j)
      *(short8*)&xk_s[(rr_ + j * 8) * 72 + c8_] = pB0[j];
#pragma unroll
    for (int j = 0; j < 2; ++j)
      pB0[j] = *(const short8*)&XKn[(tokb + 64 + rr_ + j * 8) * 1024 + col0 + c8_];
    if (wid == 4) {
      eta_s[lane] = eta_buf[(size_t)bh * 8192 + lane];
      peta = eta_buf[(size_t)bh * 8192 + 64 + lane];
    }
  }
  __syncthreads();

  for (int nc = 0; nc < 128; ++nc) {
    const int p = nc & 1;
    if (nc + 2 < 128 && ((nc + 2) & 3) == 0) {
      if (tid == 0) {
        while (__hip_atomic_load(&prog[(b << 5) + ((nc + 2) >> 2)],
                                 __ATOMIC_ACQUIRE,
                                 __HIP_MEMORY_SCOPE_AGENT) < 16u)
          __builtin_amdgcn_s_sleep(16);
      }
      bar_nowait();
    }
    const unsigned short* WTc = WT_b + p * 4608;
    unsigned short* WTn = WT_b + (p ^ 1) * 4608;
    unsigned short* xqp = xq_s + p * 4608;
    unsigned short* tgp = tg_s + p * 4608;
    unsigned short* xkp = xk_s + p * 4608;
    float* etp = eta_s + p * 64;

    // ================= phase 1 =================
    if (isA) {
      if (nc) {
#pragma unroll
        for (int n = 0; n < 4; ++n) {
          int e = n * 16 + l15;
          bstv[n] -= bpart[e] + bpart[64 + e] + bpart[128 + e] + bpart[192 + e];
        }
      }
      if (nc + 1 < 128) {
        unsigned short* xqn = xq_s + (p ^ 1) * 4608;
        unsigned short* tgn = tg_s + (p ^ 1) * 4608;
#pragma unroll
        for (int j = 0; j < 2; ++j) {
          int rr = rr_ + j * 8;
          *(short8*)&xqn[rr * 72 + c8_] = pA0[j];
          *(short8*)&tgn[rr * 72 + c8_] = pA1[j];
        }
      }
      if (nc + 2 < 128) {
#pragma unroll
        for (int j = 0; j < 2; ++j) {
          size_t g = (tokb + (nc + 2) * 64 + rr_ + j * 8) * 1024 + col0 + c8_;
          pA0[j] = *(const short8*)&XQn[g];
          pA1[j] = *(const short8*)&TGT[g];
        }
      }
      f32x4 accZ[4];
#pragma unroll
      for (int n = 0; n < 4; ++n)
        accZ[n] = (f32x4){bstv[n], bstv[n], bstv[n], bstv[n]};
      __builtin_amdgcn_s_setprio(1);
#pragma unroll
      for (int kk = 0; kk < 2; ++kk) {
        const int ko = kk * 32 + lg * 8;
        short8 a_xk = *(const short8*)&xkp[(q * 16 + l15) * 72 + ko];
#pragma unroll
        for (int n = 0; n < 4; ++n) {
          short8 b_w = *(const short8*)&WTc[(n * 16 + l15) * 72 + ko];
          accZ[n] = __builtin_amdgcn_mfma_f32_16x16x32_bf16(a_xk, b_w, accZ[n], 0, 0, 0);
        }
      }
      __builtin_amdgcn_s_setprio(0);
      float grv[4][4];
#pragma unroll
      for (int j = 0; j < 4; ++j) {
        const int r = q * 16 + lg * 4 + j;
        float z[4], s1 = 0.f, s2 = 0.f;
#pragma unroll
        for (int n = 0; n < 4; ++n) {
          z[n] = accZ[n][j];
          s1 += z[n];
          s2 += z[n] * z[n];
        }
        s1 = dpp16_sum(s1);
        s2 = dpp16_sum(s2);
        float mu = s1 * 0.015625f;
        float var = s2 * 0.015625f - mu * mu;
        float rstd = rsqrtf(var + 1e-6f);
        float xh[4], gx[4], s3 = 0.f, s4 = 0.f;
#pragma unroll
        for (int n = 0; n < 4; ++n) {
          xh[n] = (z[n] - mu) * rstd;
          float tg = bf2f(tgp[r * 72 + n * 16 + l15]);
          float go = gwv[n] * xh[n] + gbv[n] - tg;
          gx[n] = go * gwv[n];
          s3 += gx[n];
          s4 += gx[n] * xh[n];
        }
        s3 = dpp16_sum(s3);
        s4 = dpp16_sum(s4);
#pragma unroll
        for (int n = 0; n < 4; ++n)
          grv[n][j] = (64.f * gx[n] - s3 - xh[n] * s4) * rstd * 0.015625f;
      }
#pragma unroll
      for (int n = 0; n < 4; ++n) {
        us4 pk = {f2bf(grv[n][0]), f2bf(grv[n][1]), f2bf(grv[n][2]),
                  f2bf(grv[n][3])};
        *(us4*)&gradT[(n * 16 + l15) * 72 + q * 16 + lg * 4] = pk;
      }
    } else {
      if (nc + 1 < 128) {
        unsigned short* xkn = xk_s + (p ^ 1) * 4608;
#pragma unroll
        for (int j = 0; j < 2; ++j)
          *(short8*)&xkn[(rr_ + j * 8) * 72 + c8_] = pB0[j];
        if (wid == 4) eta_s[(p ^ 1) * 64 + lane] = peta;
      }
      if (nc + 2 < 128) {
#pragma unroll
        for (int j = 0; j < 2; ++j)
          pB0[j] = *(const short8*)
              &XKn[(tokb + (nc + 2) * 64 + rr_ + j * 8) * 1024 + col0 + c8_];
        if (wid == 4) peta = eta_buf[(size_t)bh * 8192 + (nc + 2) * 64 + lane];
      }
#pragma unroll
      for (int it = 0; it < 4; ++it) {
        int c0 = q * 16 + it * 4;
        us4 pk;
#pragma unroll
        for (int u = 0; u < 4; ++u)
          pk[u] = f2bf(-etp[c0 + u] * bf2f(xkp[(c0 + u) * 72 + lane]));
        *(us4*)&xkTe[lane * 72 + c0] = pk;
      }
      f32x4 accA[4];
#pragma unroll
      for (int n = 0; n < 4; ++n) accA[n] = (f32x4){0.f, 0.f, 0.f, 0.f};
      __builtin_amdgcn_s_setprio(1);
#pragma unroll
      for (int kk = 0; kk < 2; ++kk) {
        const int ko = kk * 32 + lg * 8;
        short8 a_xq = *(const short8*)&xqp[(q * 16 + l15) * 72 + ko];
#pragma unroll
        for (int n = 0; n < 4; ++n) {
          short8 b_k = *(const short8*)&xkp[(n * 16 + l15) * 72 + ko];
          accA[n] = __builtin_amdgcn_mfma_f32_16x16x32_bf16(a_xq, b_k, accA[n], 0, 0, 0);
        }
      }
      __builtin_amdgcn_s_setprio(0);
#pragma unroll
      for (int j = 0; j < 4; ++j) {
        const int r = q * 16 + lg * 4 + j;
#pragma unroll
        for (int n = 0; n < 4; ++n) {
          int cj = n * 16 + l15;
          float v = (cj <= r) ? (-etp[cj] * (1.f + accA[n][j])) : 0.f;
          gc_s[r * 72 + cj] = f2bf(v);
        }
      }
    }
    barrier_fast();  // X

    // ================= phase 2 =================
    if (isA) {
      f32x4 accZb[4];
#pragma unroll
      for (int n = 0; n < 4; ++n)
        accZb[n] = (f32x4){bstv[n], bstv[n], bstv[n], bstv[n]};
      __builtin_amdgcn_s_setprio(1);
#pragma unroll
      for (int kk = 0; kk < 2; ++kk) {
        const int ko = kk * 32 + lg * 8;
        short8 a_xq = *(const short8*)&xqp[(q * 16 + l15) * 72 + ko];
        short8 a_gc = *(const short8*)&gc_s[(q * 16 + l15) * 72 + ko];
#pragma unroll
        for (int n = 0; n < 4; ++n) {
          short8 b_w = *(const short8*)&WTc[(n * 16 + l15) * 72 + ko];
          short8 b_g = *(const short8*)&gradT[(n * 16 + l15) * 72 + ko];
          accZb[n] = __builtin_amdgcn_mfma_f32_16x16x32_bf16(a_xq, b_w, accZb[n], 0, 0, 0);
          accZb[n] = __builtin_amdgcn_mfma_f32_16x16x32_bf16(a_gc, b_g, accZb[n], 0, 0, 0);
        }
      }
      __builtin_amdgcn_s_setprio(0);
#pragma unroll
      for (int j = 0; j < 4; ++j) {
        const int r = q * 16 + lg * 4 + j;
        float z[4], s1 = 0.f, s2 = 0.f;
#pragma unroll
        for (int n = 0; n < 4; ++n) {
          z[n] = accZb[n][j];
          s1 += z[n];
          s2 += z[n] * z[n];
        }
        s1 = dpp16_sum(s1);
        s2 = dpp16_sum(s2);
        float mu = s1 * 0.015625f;
        float var = s2 * 0.015625f - mu * mu;
        float rstd = rsqrtf(var + 1e-6f);
        size_t gbase = (tokb + nc * 64 + r) * 1024 + col0;
#pragma unroll
        for (int n = 0; n < 4; ++n) {
          int e = n * 16 + l15;
          float ov = bf2f(xqp[r * 72 + e]) + gwv[n] * ((z[n] - mu) * rstd) + gbv[n];
          y[gbase + e] = (unsigned short)(cvtpk(ov, ov) & 0xffffu);
        }
      }
    } else {
      short8 a_ke[2], b_g[2][4];
#pragma unroll
      for (int kk = 0; kk < 2; ++kk) {
        const int ko = kk * 32 + lg * 8;
        a_ke[kk] = *(const short8*)&xkTe[(q * 16 + l15) * 72 + ko];
#pragma unroll
        for (int n = 0; n < 4; ++n)
          b_g[kk][n] = *(const short8*)&gradT[(n * 16 + l15) * 72 + ko];
      }
      f32x4 accW[4];
#pragma unroll
      for (int n = 0; n < 4; ++n) accW[n] = Wreg[n];
      __builtin_amdgcn_s_setprio(1);
#pragma unroll
      for (int kk = 0; kk < 2; ++kk)
#pragma unroll
        for (int n = 0; n < 4; ++n)
          accW[n] = __builtin_amdgcn_mfma_f32_16x16x32_bf16(a_ke[kk], b_g[kk][n],
                                                            accW[n], 0, 0, 0);
      __builtin_amdgcn_s_setprio(0);
#pragma unroll
      for (int n = 0; n < 4; ++n) {
        Wreg[n] = accW[n];
        us4 pk = {f2bf(accW[n][0]), f2bf(accW[n][1]), f2bf(accW[n][2]),
                  f2bf(accW[n][3])};
        *(us4*)&WTn[(n * 16 + l15) * 72 + q * 16 + lg * 4] = pk;
      }
      {
        float s = 0.f;
#pragma unroll
        for (int it = 0; it < 4; ++it) {
          us4 gv = *(const us4*)&gradT[lane * 72 + q * 16 + it * 4];
#pragma unroll
          for (int u = 0; u < 4; ++u)
            s += etp[q * 16 + it * 4 + u] * bf2f(gv[u]);
        }
        bpart[q * 64 + lane] = s;
      }
    }
    barrier_fast();  // Y
  }
}

// ---------------- generic 256x256 GEMM (output projection, tail-fixed) -----
template <int WRITE_BF16>
__global__ __launch_bounds__(512, 1) void gemm256(
    const unsigned short* __restrict__ A, const unsigned short* __restrict__ B,
    const float* __restrict__ bias, void* __restrict__ Cout,
    long M, long N, long K, int NTILN, long ldc) {
  __shared__ __align__(16) unsigned short g_lds[49152];  // 96 KB
  char* ldsc = (char*)g_lds;
  const int tid = threadIdx.x, lane = tid & 63, wid = tid >> 6;
  const int wm = wid >> 2, wn = wid & 3;
  const int l15 = lane & 15, lg = lane >> 4;

  unsigned nwg = gridDim.x, bid = blockIdx.x;
  unsigned cpx = nwg >> 3;
  unsigned swz = (bid & 7) * cpx + (bid >> 3);
  unsigned nidx = swz % (unsigned)NTILN, midx = swz / (unsigned)NTILN;
  const long m0 = (long)midx * 256, n0 = (long)nidx * 256;
  const long ldab = K * 2;

  const int srow = wid * 16 + (lane >> 2);
  const int scol = ((lane & 3) * 16) ^ (((lane >> 3) & 3) << 4);
  const int sdst = wid * 1024;
  const char* Ab = (const char*)A;
  const char* Bb = (const char*)B;

  const int acol = (lg * 16) ^ (((l15 >> 1) & 3) << 4);
  const int aro = (wm * 128 + l15) * 64 + acol;
  const int bro = 16384 + (wn * 64 + l15) * 64 + acol;

#define STG_A(tt, h, bb)                                                      \
  gload_lds16(Ab + (size_t)(m0 + (h) * 128 + srow) * ldab + (size_t)(tt) * 64 \
                  + scol,                                                     \
              ldsc + (bb) * 32768 + (h) * 8192 + sdst)
#define STG_B(tt, h, bb)                                                      \
  gload_lds16(Bb + (size_t)(n0 + (h) * 128 + srow) * ldab + (size_t)(tt) * 64 \
                  + scol,                                                     \
              ldsc + (bb) * 32768 + 16384 + (h) * 8192 + sdst)

  f32x4 acc[8][4];
#pragma unroll
  for (int m = 0; m < 8; ++m)
#pragma unroll
    for (int n = 0; n < 4; ++n) acc[m][n] = (f32x4){0.f, 0.f, 0.f, 0.f};

  const int NT = (int)(K >> 5);

  STG_A(0, 0, 0); STG_A(0, 1, 0); STG_B(0, 0, 0); STG_B(0, 1, 0);
  STG_A(1, 0, 1); STG_A(1, 1, 1); STG_B(1, 0, 1); STG_B(1, 1, 1);
  asm volatile("s_waitcnt vmcnt(4)" ::: "memory");
  bar_nowait();

  int buf = 0, sb = 2;
#pragma unroll 1
  for (int t = 0; t < NT; ++t) {
    if (t + 2 < NT) {
      STG_A(t + 2, 0, sb); STG_A(t + 2, 1, sb);
      STG_B(t + 2, 0, sb); STG_B(t + 2, 1, sb);
    }
    const char* ab = ldsc + buf * 32768 + aro;
    const char* bb2 = ldsc + buf * 32768 + bro;
    short8 av[8], bv[4];
#pragma unroll
    for (int i = 0; i < 8; ++i) av[i] = *(const short8*)(ab + i * 1024);
#pragma unroll
    for (int nf = 0; nf < 4; ++nf) bv[nf] = *(const short8*)(bb2 + nf * 1024);
    __builtin_amdgcn_s_setprio(1);
#pragma unroll
    for (int i = 0; i < 8; ++i)
#pragma unroll
      for (int nf = 0; nf < 4; ++nf)
        acc[i][nf] = __builtin_amdgcn_mfma_f32_16x16x32_bf16(av[i], bv[nf],
                                                             acc[i][nf], 0, 0, 0);
    __builtin_amdgcn_s_setprio(0);
    if (t < NT - 2)
      asm volatile("s_waitcnt vmcnt(4)" ::: "memory");
    else
      asm volatile("s_waitcnt vmcnt(0)" ::: "memory");  // tail: all landed
    bar_nowait();
    buf = (buf == 2) ? 0 : buf + 1;
    sb = (sb == 2) ? 0 : sb + 1;
  }
#undef STG_A
#undef STG_B

#pragma unroll
  for (int mf = 0; mf < 8; ++mf) {
    long r0 = m0 + wm * 128 + mf * 16 + lg * 4;
#pragma unroll
    for (int nf = 0; nf < 4; ++nf) {
      long c = n0 + wn * 64 + nf * 16 + l15;
      float bvv = bias ? bias[c] : 0.f;
#pragma unroll
      for (int j = 0; j < 4; ++j) {
        float v = acc[mf][nf][j] + bvv;
        if (WRITE_BF16)
          ((unsigned short*)Cout)[(r0 + j) * ldc + c] = f2bf(v);
        else
          ((float*)Cout)[(r0 + j) * ldc + c] = v;
      }
    }
  }
}

// ---------------- post layernorm over D=1024 (bf16 in) ---------------------
__global__ __launch_bounds__(256) void postnorm(
    const unsigned short* __restrict__ yv, const float* __restrict__ pw,
    const float* __restrict__ pb, unsigned short* __restrict__ yn) {
  int t = blockIdx.x;
  int tid = threadIdx.x, lane = tid & 63, wid = tid >> 6;
  us4 v4 = *(const us4*)&yv[(size_t)t * 1024 + tid * 4];
  float v[4];
  float s1 = 0.f, s2 = 0.f;
#pragma unroll
  for (int u = 0; u < 4; ++u) {
    v[u] = bf2f(v4[u]);
    s1 += v[u];
    s2 += v[u] * v[u];
  }
#pragma unroll
  for (int o = 1; o < 64; o <<= 1) {
    s1 += __shfl_xor(s1, o);
    s2 += __shfl_xor(s2, o);
  }
  __shared__ float r1[4], r2[4];
  if (lane == 0) {
    r1[wid] = s1;
    r2[wid] = s2;
  }
  __syncthreads();
  s1 = r1[0] + r1[1] + r1[2] + r1[3];
  s2 = r2[0] + r2[1] + r2[2] + r2[3];
  float mu = s1 * (1.f / 1024.f);
  float var = s2 * (1.f / 1024.f) - mu * mu;
  float rstd = rsqrtf(var + 1e-6f);
  int c = tid * 4;
  us4 o4;
#pragma unroll
  for (int u = 0; u < 4; ++u)
    o4[u] = f2bf(pw[c + u] * ((v[u] - mu) * rstd) + pb[c + u]);
  *(us4*)&yn[(size_t)t * 1024 + c] = o4;
}

// ---------------------------------------------------------------------------
extern "C" void kernel_launch(void* const* d_in, const int* in_sizes, int n_in,
                              void* d_out, int out_size, void* d_ws,
                              size_t ws_size, hipStream_t stream) {
  const float* hs  = (const float*)d_in[0];
  const float* wqw = (const float*)d_in[1];
  const float* wqb = (const float*)d_in[2];
  const float* wkw = (const float*)d_in[3];
  const float* wkb = (const float*)d_in[4];
  const float* wvw = (const float*)d_in[5];
  const float* wvb = (const float*)d_in[6];
  const float* wow = (const float*)d_in[7];
  const float* wob = (const float*)d_in[8];
  const float* tnw = (const float*)d_in[9];
  const float* tnb = (const float*)d_in[10];
  const float* lrw = (const float*)d_in[11];
  const float* lrb = (const float*)d_in[12];
  const float* W1  = (const float*)d_in[13];
  const float* b1  = (const float*)d_in[14];
  const float* pnw = (const float*)d_in[15];
  const float* pnb = (const float*)d_in[16];

  // layout: XQ(64M)[->ynorm] | XK(64M) | TGT(64M) | eta(2M) | wo(2M) |
  //         prog(4K) | hs_bf(64M) | Wcat(8M) | biasc(16K) | ybf(64M)
  const size_t OFF_XQ    = 0;
  const size_t OFF_XK    = 67108864;
  const size_t OFF_TGT   = 134217728;
  const size_t OFF_ETA   = 201326592;
  const size_t OFF_WOBF  = 203423744;
  const size_t OFF_PROG  = 205520896;
  const size_t OFF_HSBF  = 205524992;
  const size_t OFF_WCAT  = OFF_HSBF + 67108864;
  const size_t OFF_BIASC = OFF_WCAT + 8388608;
  const size_t OFF_YBF   = OFF_BIASC + 16384;
  const size_t NEEDED    = OFF_YBF + 67108864;
  if (ws_size < NEEDED) return;

  char* ws = (char*)d_ws;
  unsigned short* XQn   = (unsigned short*)(ws + OFF_XQ);
  unsigned short* ynorm = (unsigned short*)(ws + OFF_XQ);   // alias after scan
  unsigned short* XKn   = (unsigned short*)(ws + OFF_XK);
  unsigned short* TGT   = (unsigned short*)(ws + OFF_TGT);
  float* eta_buf        = (float*)(ws + OFF_ETA);
  unsigned short* wo_bf = (unsigned short*)(ws + OFF_WOBF);
  unsigned int* prog    = (unsigned int*)(ws + OFF_PROG);
  unsigned short* hs_bf = (unsigned short*)(ws + OFF_HSBF);
  unsigned short* Wcat  = (unsigned short*)(ws + OFF_WCAT);
  float* biasc          = (float*)(ws + OFF_BIASC);
  unsigned short* ybf   = (unsigned short*)(ws + OFF_YBF);

  cvt_f32_bf16<<<32768, 256, 0, stream>>>(hs, hs_bf, 33554432L);
  build_wcat<<<16384, 256, 0, stream>>>(wqw, wkw, wvw, lrw, wqb, wkb, wvb, lrb,
                                        Wcat, biasc);
  cvt_f32_bf16<<<1024, 256, 0, stream>>>(wow, wo_bf, 1048576L);
  hipMemsetAsync(prog, 0, 4096, stream);
  qkv_scan<<<2112, 512, 0, stream>>>(hs_bf, Wcat, biasc, tnw, tnb,
                                     XQn, XKn, TGT, eta_buf, W1, b1, ybf, prog);
  postnorm<<<32768, 256, 0, stream>>>(ybf, pnw, pnb, ynorm);
  gemm256<0><<<512, 512, 0, stream>>>(ynorm, wo_bf, wob, d_out,
                                      32768L, 1024L, 1024L, 4, 1024L);
}